// Round 9
// baseline (1535.934 us; speedup 1.0000x reference)
//
#include <hip/hip_runtime.h>

#define HH 1024
#define WW 1024
#define RAD 8
#define EPSF 1e-4f
#define HWSZ (HH * WW)
#define NPLB 16  // ws planes per batch (boxed a/b only)
#define T2 216   // output cols per wave
#define NTL 5    // tiles per row (216*5 = 1080 >= 1024)
#define RROWS 4  // rows per wave, k_stats_solve
#define V3R 32   // rows per block, k_vbox_comb

__device__ __forceinline__ float4 f4add(float4 a, float4 b) {
  return make_float4(a.x + b.x, a.y + b.y, a.z + b.z, a.w + b.w);
}
__device__ __forceinline__ float4 f4sub(float4 a, float4 b) {
  return make_float4(a.x - b.x, a.y - b.y, a.z - b.z, a.w - b.w);
}
__device__ __forceinline__ float4 f4mul(float4 a, float4 b) {
  return make_float4(a.x * b.x, a.y * b.y, a.z * b.z, a.w * b.w);
}
__device__ __forceinline__ float4 f4adds(float4 a, float c) {
  return make_float4(a.x + c, a.y + c, a.z + c, a.w + c);
}
__device__ __forceinline__ float4 f4scale(float4 a, float c) {
  return make_float4(a.x * c, a.y * c, a.z * c, a.w * c);
}

// Inclusive wave64 prefix scan via DPP (VALU-only, no LDS pipe).
__device__ __forceinline__ float wave_incl_scan(float v) {
  int t;
  t = __builtin_amdgcn_update_dpp(0, __float_as_int(v), 0x111, 0xf, 0xf, false);
  v += __int_as_float(t);
  t = __builtin_amdgcn_update_dpp(0, __float_as_int(v), 0x112, 0xf, 0xf, false);
  v += __int_as_float(t);
  t = __builtin_amdgcn_update_dpp(0, __float_as_int(v), 0x114, 0xf, 0xf, false);
  v += __int_as_float(t);
  t = __builtin_amdgcn_update_dpp(0, __float_as_int(v), 0x118, 0xf, 0xf, false);
  v += __int_as_float(t);
  t = __builtin_amdgcn_update_dpp(0, __float_as_int(v), 0x142, 0xa, 0xf, false);
  v += __int_as_float(t);
  t = __builtin_amdgcn_update_dpp(0, __float_as_int(v), 0x143, 0xc, 0xf, false);
  v += __int_as_float(t);
  return v;
}

struct TapsA { float h0, h1, h2, h3, l1, l2, l3, pw; };
struct TapsB { float h0, h1, h2, h3, lm, pw; };

// prefix over 4 per-thread cols: P = {P0,P1,P2,P3} (P3 = incl total)
__device__ __forceinline__ float4 pre4(float4 v) {
  const float s1 = v.x + v.y, s2 = s1 + v.z, ts = s2 + v.w;
  const float incl = wave_incl_scan(ts);
  const float base = incl - ts;
  return make_float4(base + v.x, base + s1, base + s2, incl);
}

// ---------------- K_A: sliding vbox(25 products) + hbox(25) + 3x3 solve
// + hbox(a/b), with software-pipelined shuffle chains.
__global__ __launch_bounds__(256, 4) void k_stats_solve(
    const float* __restrict__ x, const float* __restrict__ g,
    float* __restrict__ ws, int b0) {
  const int lane = threadIdx.x & 63;
  const int w = threadIdx.x >> 6;
  const int bi = blockIdx.y;
  const int gw = blockIdx.x * 4 + w;
  const int rowblk = gw / NTL;
  const int tix = gw - rowblk * NTL;
  const int y0 = rowblk * RROWS;
  const int b = b0 + bi;
  float* wsb = ws + (size_t)bi * NPLB * HWSZ;
  const int F = tix * T2;
  const int E = F - 20;
  const int relmax = (WW - 1) - E;
  const int col0 = E + 4 * lane;
  const bool ldok = (col0 >= 0) && (col0 < WW);

  const float* gp0 = g + (size_t)(b * 3 + 0) * HWSZ;
  const float* gp1 = g + (size_t)(b * 3 + 1) * HWSZ;
  const float* gp2 = g + (size_t)(b * 3 + 2) * HWSZ;
  const float* sp0 = x + (size_t)(b * 4 + 0) * HWSZ;
  const float* sp1 = x + (size_t)(b * 4 + 1) * HWSZ;
  const float* sp2 = x + (size_t)(b * 4 + 2) * HWSZ;
  const float* sp3 = x + (size_t)(b * 4 + 3) * HWSZ;

  const int cbase = E + 12 + 4 * lane;
  float4 nxinvv;
  {
    float t[4];
#pragma unroll
    for (int j = 0; j < 4; ++j) {
      const int c = cbase + j;
      const int nx = min(c + RAD, WW - 1) - max(c - RAD, 0) + 1;
      t[j] = 1.0f / (float)nx;
    }
    nxinvv = make_float4(t[0], t[1], t[2], t[3]);
  }
  const bool abok = (lane <= 58) && (cbase >= 0) && (cbase < WW);
  const int qmax = relmax - 12;
  const int nstore = min(54, (WW - F) >> 2);
  const bool stok = lane < nstore;
  const int pwlA = min(relmax >> 2, 63);
  const int pwlB = min(qmax >> 2, 63);
  const int r0 = 4 * lane + 12;
  const int qf0 = 8 + 4 * lane;
  const bool ha0 = (r0 + 8 <= relmax), ha1 = (r0 + 9 <= relmax),
             ha2 = (r0 + 10 <= relmax), ha3 = (r0 + 11 <= relmax);
  const bool la0 = (E + r0 >= 9), la1 = (E + r0 + 1 >= 9),
             la2 = (E + r0 + 2 >= 9), la3 = (E + r0 + 3 >= 9);
  const bool hb0 = (qf0 + 8 <= qmax), hb1 = (qf0 + 9 <= qmax),
             hb2 = (qf0 + 10 <= qmax), hb3 = (qf0 + 11 <= qmax);
  const bool lb0 = (qf0 >= 9);

  auto tapsA = [&](float4 P) -> TapsA {
    TapsA t;
    t.h0 = __shfl(P.x, lane + 5); t.h1 = __shfl(P.y, lane + 5);
    t.h2 = __shfl(P.z, lane + 5); t.h3 = __shfl(P.w, lane + 5);
    t.l1 = __shfl(P.x, lane + 1); t.l2 = __shfl(P.y, lane + 1);
    t.l3 = __shfl(P.z, lane + 1);
    t.pw = __shfl(P.w, pwlA);
    return t;
  };
  auto consA = [&](float4 P, TapsA t) -> float4 {
    float4 o;
    o.x = (ha0 ? t.h0 : t.pw) - (la0 ? P.w : 0.f);
    o.y = (ha1 ? t.h1 : t.pw) - (la1 ? t.l1 : 0.f);
    o.z = (ha2 ? t.h2 : t.pw) - (la2 ? t.l2 : 0.f);
    o.w = (ha3 ? t.h3 : t.pw) - (la3 ? t.l3 : 0.f);
    return o;
  };
  auto tapsB = [&](float4 Q) -> TapsB {
    TapsB u;
    u.h0 = __shfl(Q.x, lane + 4); u.h1 = __shfl(Q.y, lane + 4);
    u.h2 = __shfl(Q.z, lane + 4); u.h3 = __shfl(Q.w, lane + 4);
    u.lm = __shfl(Q.w, lane - 1);
    u.pw = __shfl(Q.w, pwlB);
    return u;
  };
  auto consB = [&](float4 Q, TapsB u) -> float4 {
    float4 o;
    o.x = (hb0 ? u.h0 : u.pw) - (lb0 ? u.lm : 0.f);
    o.y = (hb1 ? u.h1 : u.pw) - Q.x;
    o.z = (hb2 ? u.h2 : u.pw) - Q.y;
    o.w = (hb3 ? u.h3 : u.pw) - Q.z;
    return o;
  };

  // sliding vertical sums of the 25 product channels
  float4 s[25];
#pragma unroll
  for (int i = 0; i < 25; ++i) s[i] = make_float4(0.f, 0.f, 0.f, 0.f);
  const float4 Z4 = make_float4(0.f, 0.f, 0.f, 0.f);

  auto row_acc = [&](int yy, bool add) {
    if (yy < 0 || yy >= HH) return;
    const int off = yy * WW + col0;
    const float4 G0 = ldok ? *(const float4*)(gp0 + off) : Z4;
    const float4 G1 = ldok ? *(const float4*)(gp1 + off) : Z4;
    const float4 G2 = ldok ? *(const float4*)(gp2 + off) : Z4;
    const float4 S0 = ldok ? *(const float4*)(sp0 + off) : Z4;
    const float4 S1 = ldok ? *(const float4*)(sp1 + off) : Z4;
    const float4 S2 = ldok ? *(const float4*)(sp2 + off) : Z4;
    const float4 S3 = ldok ? *(const float4*)(sp3 + off) : Z4;
#define ACC(idx, val)                                       \
  do {                                                      \
    const float4 t_ = (val);                                \
    s[idx] = add ? f4add(s[idx], t_) : f4sub(s[idx], t_);   \
  } while (0)
    ACC(0, G0); ACC(1, G1); ACC(2, G2);
    ACC(3, S0); ACC(4, S1); ACC(5, S2); ACC(6, S3);
    ACC(7, f4mul(G0, S0)); ACC(8, f4mul(G0, S1));
    ACC(9, f4mul(G0, S2)); ACC(10, f4mul(G0, S3));
    ACC(11, f4mul(G1, S0)); ACC(12, f4mul(G1, S1));
    ACC(13, f4mul(G1, S2)); ACC(14, f4mul(G1, S3));
    ACC(15, f4mul(G2, S0)); ACC(16, f4mul(G2, S1));
    ACC(17, f4mul(G2, S2)); ACC(18, f4mul(G2, S3));
    ACC(19, f4mul(G0, G0)); ACC(20, f4mul(G0, G1)); ACC(21, f4mul(G0, G2));
    ACC(22, f4mul(G1, G1)); ACC(23, f4mul(G1, G2)); ACC(24, f4mul(G2, G2));
#undef ACC
  };

  for (int yy = y0 - RAD; yy <= y0 + RAD; ++yy) row_acc(yy, true);

  for (int row = y0; row < y0 + RROWS; ++row) {
    const int ny = min(row + RAD, HH - 1) - max(row - RAD, 0) + 1;
    const float4 invNv = f4scale(nxinvv, 1.0f / (float)ny);

    // ---- group 1: ch 0,1,2 (means) + 19..24 (cov), pipelined 1-deep ----
    float4 Pa = pre4(s[0]); TapsA Ta = tapsA(Pa);
    float4 Pb = pre4(s[1]);
    const float4 c0 = consA(Pa, Ta); TapsA Tb = tapsA(Pb);
    Pa = pre4(s[2]);
    const float4 c1 = consA(Pb, Tb); Ta = tapsA(Pa);
    Pb = pre4(s[19]);
    const float4 c2 = consA(Pa, Ta); Tb = tapsA(Pb);
    Pa = pre4(s[20]);
    const float4 t19 = consA(Pb, Tb); Ta = tapsA(Pa);
    Pb = pre4(s[21]);
    const float4 t20 = consA(Pa, Ta); Tb = tapsA(Pb);
    Pa = pre4(s[22]);
    const float4 t21 = consA(Pb, Tb); Ta = tapsA(Pa);
    Pb = pre4(s[23]);
    const float4 t22 = consA(Pa, Ta); Tb = tapsA(Pb);
    Pa = pre4(s[24]);
    const float4 t23 = consA(Pb, Tb); Ta = tapsA(Pa);
    const float4 t24 = consA(Pa, Ta);

    const float4 mI0 = f4mul(c0, invNv);
    const float4 mI1 = f4mul(c1, invNv);
    const float4 mI2 = f4mul(c2, invNv);
#define M(a, b) f4mul(a, b)
    const float4 rr = f4adds(f4sub(M(t19, invNv), M(mI0, mI0)), EPSF);
    const float4 rg = f4sub(M(t20, invNv), M(mI0, mI1));
    const float4 rb = f4sub(M(t21, invNv), M(mI0, mI2));
    const float4 gg = f4adds(f4sub(M(t22, invNv), M(mI1, mI1)), EPSF);
    const float4 gb = f4sub(M(t23, invNv), M(mI1, mI2));
    const float4 bb = f4adds(f4sub(M(t24, invNv), M(mI2, mI2)), EPSF);
    const float4 det = f4sub(
        f4sub(f4sub(f4add(M(M(rr, gg), bb), f4scale(M(M(rg, gb), rb), 2.f)),
                    M(M(rb, gg), rb)),
              M(M(rg, rg), bb)),
        M(M(rr, gb), gb));
    const float4 idet =
        make_float4(1.f / det.x, 1.f / det.y, 1.f / det.z, 1.f / det.w);
    const float4 iv0 = M(f4sub(M(gg, bb), M(gb, gb)), idet);
    const float4 iv1 = M(f4sub(M(rb, gb), M(rg, bb)), idet);
    const float4 iv2 = M(f4sub(M(rg, gb), M(rb, gg)), idet);
    const float4 iv3 = M(f4sub(M(rr, bb), M(rb, rb)), idet);
    const float4 iv4 = M(f4sub(M(rb, rg), M(rr, gb)), idet);
    const float4 iv5 = M(f4sub(M(rr, gg), M(rg, rg)), idet);

    const size_t obase = (size_t)row * WW + F + 4 * lane;
    auto stB = [&](float4 o, int plane) {
      if (stok) *(float4*)(wsb + (size_t)plane * HWSZ + obase) = o;
    };

    // ---- per-src-channel: 4 A-chains -> solve -> 4 B-chains, pipelined ----
#pragma unroll
    for (int cc = 0; cc < 4; ++cc) {
      float4 Pc = pre4(s[3 + cc]); TapsA Tc = tapsA(Pc);
      float4 Pd = pre4(s[7 + cc]);
      const float4 tmp = consA(Pc, Tc); TapsA Td = tapsA(Pd);
      Pc = pre4(s[11 + cc]);
      const float4 tq0 = consA(Pd, Td); Tc = tapsA(Pc);
      Pd = pre4(s[15 + cc]);
      const float4 tq1 = consA(Pc, Tc); Td = tapsA(Pd);
      const float4 tq2 = consA(Pd, Td);

      const float4 m = M(tmp, invNv);
      const float4 cv0 = f4sub(M(tq0, invNv), M(mI0, m));
      const float4 cv1 = f4sub(M(tq1, invNv), M(mI1, m));
      const float4 cv2 = f4sub(M(tq2, invNv), M(mI2, m));
      float4 a0 = f4add(f4add(M(cv0, iv0), M(cv1, iv1)), M(cv2, iv2));
      float4 a1 = f4add(f4add(M(cv0, iv1), M(cv1, iv3)), M(cv2, iv4));
      float4 a2 = f4add(f4add(M(cv0, iv2), M(cv1, iv4)), M(cv2, iv5));
      float4 bv = f4sub(m, f4add(f4add(M(a0, mI0), M(a1, mI1)), M(a2, mI2)));
      a0 = abok ? a0 : Z4;
      a1 = abok ? a1 : Z4;
      a2 = abok ? a2 : Z4;
      bv = abok ? bv : Z4;

      float4 Qa = pre4(a0); TapsB Ua = tapsB(Qa);
      float4 Qb = pre4(a1);
      stB(consB(Qa, Ua), cc); TapsB Ub = tapsB(Qb);
      Qa = pre4(a2);
      stB(consB(Qb, Ub), 4 + cc); Ua = tapsB(Qa);
      Qb = pre4(bv);
      stB(consB(Qa, Ua), 8 + cc); Ub = tapsB(Qb);
      stB(consB(Qb, Ub), 12 + cc);
    }
#undef M

    row_acc(row + RAD + 1, true);
    row_acc(row - RAD, false);
  }
}

// ---------------- K_B: vertical box of boxed a/b + combine, channel-split.
// blockIdx.z = bi*4 + cc; each block needs only planes {cc,4+cc,8+cc,12+cc}.
__global__ __launch_bounds__(256) void k_vbox_comb(const float* __restrict__ ws_,
                                                   const float* __restrict__ g,
                                                   float* __restrict__ out, int b0) {
  const int col = blockIdx.x * 256 + threadIdx.x;
  const int y0 = blockIdx.y * V3R;
  const int zz = blockIdx.z;
  const int bi = zz >> 2;
  const int cc = zz & 3;
  const int b = b0 + bi;
  const float* A0 = ws_ + (size_t)bi * NPLB * HWSZ + (size_t)cc * HWSZ;
  const float* A1 = A0 + (size_t)4 * HWSZ;
  const float* A2 = A0 + (size_t)8 * HWSZ;
  const float* Bp = A0 + (size_t)12 * HWSZ;
  const float* gp0 = g + (size_t)(b * 3 + 0) * HWSZ;
  const float* gp1 = g + (size_t)(b * 3 + 1) * HWSZ;
  const float* gp2 = g + (size_t)(b * 3 + 2) * HWSZ;
  float* op = out + (size_t)(b * 4 + cc) * HWSZ;

  float a0 = 0.f, a1 = 0.f, a2 = 0.f, ab = 0.f;
  auto row_op = [&](int y, bool add) {
    const int off = y * WW + col;
    const float v0 = A0[off], v1 = A1[off], v2 = A2[off], v3 = Bp[off];
    if (add) { a0 += v0; a1 += v1; a2 += v2; ab += v3; }
    else     { a0 -= v0; a1 -= v1; a2 -= v2; ab -= v3; }
  };

  for (int yy = y0 - RAD; yy <= y0 + RAD; ++yy)
    if (yy >= 0 && yy < HH) row_op(yy, true);

  const int nx = min(col + RAD, WW - 1) - max(col - RAD, 0) + 1;
  const float invnx = 1.0f / (float)nx;

  for (int y = y0; y < y0 + V3R; ++y) {
    const int ny = min(y + RAD, HH - 1) - max(y - RAD, 0) + 1;
    const float invN = invnx / (float)ny;
    const size_t off = (size_t)y * WW + col;
    const float g0 = gp0[off], g1 = gp1[off], g2 = gp2[off];
    op[off] = (a0 * g0 + a1 * g1 + a2 * g2 + ab) * invN;
    const int ye = y + RAD + 1;
    if (ye < HH) row_op(ye, true);
    const int yl = y - RAD;
    if (yl >= 0) row_op(yl, false);
  }
}

extern "C" void kernel_launch(void* const* d_in, const int* in_sizes, int n_in,
                              void* d_out, int out_size, void* d_ws, size_t ws_size,
                              hipStream_t stream) {
  const float* x = (const float*)d_in[0];   // (4,4,1024,1024) src p
  const float* g = (const float*)d_in[1];   // (4,3,1024,1024) guide
  float* out = (float*)d_out;
  float* ws = (float*)d_ws;
  const size_t perBatchBytes = (size_t)NPLB * HWSZ * sizeof(float);  // 64 MB
  int nb = (int)(ws_size / perBatchBytes);
  if (nb < 1) nb = 1;
  if (nb > 4) nb = 4;
  for (int b0 = 0; b0 < 4; b0 += nb) {
    const int nbc = (4 - b0 < nb) ? (4 - b0) : nb;
    dim3 gA((HH / RROWS) * NTL / 4, nbc);
    dim3 gB(WW / 256, HH / V3R, nbc * 4);
    hipLaunchKernelGGL(k_stats_solve, gA, dim3(256), 0, stream, x, g, ws, b0);
    hipLaunchKernelGGL(k_vbox_comb, gB, dim3(256), 0, stream, ws, g, out, b0);
  }
}

// Round 10
// 583.219 us; speedup vs baseline: 2.6335x; 2.6335x over previous
//
#include <hip/hip_runtime.h>

#define HH 1024
#define WW 1024
#define RAD 8
#define EPSF 1e-4f
#define HWSZ (HH * WW)
#define NPLB 16  // ws planes per batch (4 cc-packs of [H][W][4])
#define T2 216   // output cols per wave
#define NTL 5    // tiles per row (216*5 = 1080 >= 1024)
#define RROWS 8  // rows per wave, k_stats_solve
#define V3R 32   // rows per block, k_vbox_comb

__device__ __forceinline__ float4 f4add(float4 a, float4 b) {
  return make_float4(a.x + b.x, a.y + b.y, a.z + b.z, a.w + b.w);
}
__device__ __forceinline__ float4 f4sub(float4 a, float4 b) {
  return make_float4(a.x - b.x, a.y - b.y, a.z - b.z, a.w - b.w);
}
__device__ __forceinline__ float4 f4mul(float4 a, float4 b) {
  return make_float4(a.x * b.x, a.y * b.y, a.z * b.z, a.w * b.w);
}
__device__ __forceinline__ float4 f4adds(float4 a, float c) {
  return make_float4(a.x + c, a.y + c, a.z + c, a.w + c);
}
__device__ __forceinline__ float4 f4scale(float4 a, float c) {
  return make_float4(a.x * c, a.y * c, a.z * c, a.w * c);
}

// Inclusive wave64 prefix scan via DPP (VALU-only, no LDS pipe).
__device__ __forceinline__ float wave_incl_scan(float v) {
  int t;
  t = __builtin_amdgcn_update_dpp(0, __float_as_int(v), 0x111, 0xf, 0xf, false);
  v += __int_as_float(t);
  t = __builtin_amdgcn_update_dpp(0, __float_as_int(v), 0x112, 0xf, 0xf, false);
  v += __int_as_float(t);
  t = __builtin_amdgcn_update_dpp(0, __float_as_int(v), 0x114, 0xf, 0xf, false);
  v += __int_as_float(t);
  t = __builtin_amdgcn_update_dpp(0, __float_as_int(v), 0x118, 0xf, 0xf, false);
  v += __int_as_float(t);
  t = __builtin_amdgcn_update_dpp(0, __float_as_int(v), 0x142, 0xa, 0xf, false);
  v += __int_as_float(t);
  t = __builtin_amdgcn_update_dpp(0, __float_as_int(v), 0x143, 0xc, 0xf, false);
  v += __int_as_float(t);
  return v;
}

struct TapsA { float h0, h1, h2, h3, l1, l2, l3, pw; };
struct TapsB { float h0, h1, h2, h3, lm, pw; };

// prefix over 4 per-thread cols: P = {P0,P1,P2,P3} (P3 = incl total)
__device__ __forceinline__ float4 pre4(float4 v) {
  const float s1 = v.x + v.y, s2 = s1 + v.z, ts = s2 + v.w;
  const float incl = wave_incl_scan(ts);
  const float base = incl - ts;
  return make_float4(base + v.x, base + s1, base + s2, incl);
}

// ---------------- K_A: sliding vbox(25 products) + hbox(25) + 3x3 solve
// + hbox(a/b), software-pipelined shuffle chains, packed [cc][H][W][4] out.
__global__ __launch_bounds__(256, 2) void k_stats_solve(
    const float* __restrict__ x, const float* __restrict__ g,
    float* __restrict__ ws, int b0) {
  const int lane = threadIdx.x & 63;
  const int w = threadIdx.x >> 6;
  const int bi = blockIdx.y;
  const int gw = blockIdx.x * 4 + w;
  const int rowblk = gw / NTL;
  const int tix = gw - rowblk * NTL;
  const int y0 = rowblk * RROWS;
  const int b = b0 + bi;
  float* wsb = ws + (size_t)bi * NPLB * HWSZ;
  const int F = tix * T2;
  const int E = F - 20;
  const int relmax = (WW - 1) - E;
  const int col0 = E + 4 * lane;
  const bool ldok = (col0 >= 0) && (col0 < WW);

  const float* gp0 = g + (size_t)(b * 3 + 0) * HWSZ;
  const float* gp1 = g + (size_t)(b * 3 + 1) * HWSZ;
  const float* gp2 = g + (size_t)(b * 3 + 2) * HWSZ;
  const float* sp0 = x + (size_t)(b * 4 + 0) * HWSZ;
  const float* sp1 = x + (size_t)(b * 4 + 1) * HWSZ;
  const float* sp2 = x + (size_t)(b * 4 + 2) * HWSZ;
  const float* sp3 = x + (size_t)(b * 4 + 3) * HWSZ;

  const int cbase = E + 12 + 4 * lane;
  float4 nxinvv;
  {
    float t[4];
#pragma unroll
    for (int j = 0; j < 4; ++j) {
      const int c = cbase + j;
      const int nx = min(c + RAD, WW - 1) - max(c - RAD, 0) + 1;
      t[j] = 1.0f / (float)nx;
    }
    nxinvv = make_float4(t[0], t[1], t[2], t[3]);
  }
  const bool abok = (lane <= 58) && (cbase >= 0) && (cbase < WW);
  const int qmax = relmax - 12;
  const int nstore = min(54, (WW - F) >> 2);
  const bool stok = lane < nstore;
  const int pwlA = min(relmax >> 2, 63);
  const int pwlB = min(qmax >> 2, 63);
  const int r0 = 4 * lane + 12;
  const int qf0 = 8 + 4 * lane;
  const bool ha0 = (r0 + 8 <= relmax), ha1 = (r0 + 9 <= relmax),
             ha2 = (r0 + 10 <= relmax), ha3 = (r0 + 11 <= relmax);
  const bool la0 = (E + r0 >= 9), la1 = (E + r0 + 1 >= 9),
             la2 = (E + r0 + 2 >= 9), la3 = (E + r0 + 3 >= 9);
  const bool hb0 = (qf0 + 8 <= qmax), hb1 = (qf0 + 9 <= qmax),
             hb2 = (qf0 + 10 <= qmax), hb3 = (qf0 + 11 <= qmax);
  const bool lb0 = (qf0 >= 9);

  auto tapsA = [&](float4 P) -> TapsA {
    TapsA t;
    t.h0 = __shfl(P.x, lane + 5); t.h1 = __shfl(P.y, lane + 5);
    t.h2 = __shfl(P.z, lane + 5); t.h3 = __shfl(P.w, lane + 5);
    t.l1 = __shfl(P.x, lane + 1); t.l2 = __shfl(P.y, lane + 1);
    t.l3 = __shfl(P.z, lane + 1);
    t.pw = __shfl(P.w, pwlA);
    return t;
  };
  auto consA = [&](float4 P, TapsA t) -> float4 {
    float4 o;
    o.x = (ha0 ? t.h0 : t.pw) - (la0 ? P.w : 0.f);
    o.y = (ha1 ? t.h1 : t.pw) - (la1 ? t.l1 : 0.f);
    o.z = (ha2 ? t.h2 : t.pw) - (la2 ? t.l2 : 0.f);
    o.w = (ha3 ? t.h3 : t.pw) - (la3 ? t.l3 : 0.f);
    return o;
  };
  auto tapsB = [&](float4 Q) -> TapsB {
    TapsB u;
    u.h0 = __shfl(Q.x, lane + 4); u.h1 = __shfl(Q.y, lane + 4);
    u.h2 = __shfl(Q.z, lane + 4); u.h3 = __shfl(Q.w, lane + 4);
    u.lm = __shfl(Q.w, lane - 1);
    u.pw = __shfl(Q.w, pwlB);
    return u;
  };
  auto consB = [&](float4 Q, TapsB u) -> float4 {
    float4 o;
    o.x = (hb0 ? u.h0 : u.pw) - (lb0 ? u.lm : 0.f);
    o.y = (hb1 ? u.h1 : u.pw) - Q.x;
    o.z = (hb2 ? u.h2 : u.pw) - Q.y;
    o.w = (hb3 ? u.h3 : u.pw) - Q.z;
    return o;
  };

  // sliding vertical sums of the 25 product channels
  float4 s[25];
#pragma unroll
  for (int i = 0; i < 25; ++i) s[i] = make_float4(0.f, 0.f, 0.f, 0.f);
  const float4 Z4 = make_float4(0.f, 0.f, 0.f, 0.f);

  auto row_acc = [&](int yy, bool add) {
    if (yy < 0 || yy >= HH) return;
    const int off = yy * WW + col0;
    const float4 G0 = ldok ? *(const float4*)(gp0 + off) : Z4;
    const float4 G1 = ldok ? *(const float4*)(gp1 + off) : Z4;
    const float4 G2 = ldok ? *(const float4*)(gp2 + off) : Z4;
    const float4 S0 = ldok ? *(const float4*)(sp0 + off) : Z4;
    const float4 S1 = ldok ? *(const float4*)(sp1 + off) : Z4;
    const float4 S2 = ldok ? *(const float4*)(sp2 + off) : Z4;
    const float4 S3 = ldok ? *(const float4*)(sp3 + off) : Z4;
#define ACC(idx, val)                                       \
  do {                                                      \
    const float4 t_ = (val);                                \
    s[idx] = add ? f4add(s[idx], t_) : f4sub(s[idx], t_);   \
  } while (0)
    ACC(0, G0); ACC(1, G1); ACC(2, G2);
    ACC(3, S0); ACC(4, S1); ACC(5, S2); ACC(6, S3);
    ACC(7, f4mul(G0, S0)); ACC(8, f4mul(G0, S1));
    ACC(9, f4mul(G0, S2)); ACC(10, f4mul(G0, S3));
    ACC(11, f4mul(G1, S0)); ACC(12, f4mul(G1, S1));
    ACC(13, f4mul(G1, S2)); ACC(14, f4mul(G1, S3));
    ACC(15, f4mul(G2, S0)); ACC(16, f4mul(G2, S1));
    ACC(17, f4mul(G2, S2)); ACC(18, f4mul(G2, S3));
    ACC(19, f4mul(G0, G0)); ACC(20, f4mul(G0, G1)); ACC(21, f4mul(G0, G2));
    ACC(22, f4mul(G1, G1)); ACC(23, f4mul(G1, G2)); ACC(24, f4mul(G2, G2));
#undef ACC
  };

  for (int yy = y0 - RAD; yy <= y0 + RAD; ++yy) row_acc(yy, true);

  for (int row = y0; row < y0 + RROWS; ++row) {
    const int ny = min(row + RAD, HH - 1) - max(row - RAD, 0) + 1;
    const float4 invNv = f4scale(nxinvv, 1.0f / (float)ny);

    // ---- group 1: ch 0,1,2 (means) + 19..24 (cov), pipelined 1-deep ----
    float4 Pa = pre4(s[0]); TapsA Ta = tapsA(Pa);
    float4 Pb = pre4(s[1]);
    const float4 c0 = consA(Pa, Ta); TapsA Tb = tapsA(Pb);
    Pa = pre4(s[2]);
    const float4 c1 = consA(Pb, Tb); Ta = tapsA(Pa);
    Pb = pre4(s[19]);
    const float4 c2 = consA(Pa, Ta); Tb = tapsA(Pb);
    Pa = pre4(s[20]);
    const float4 t19 = consA(Pb, Tb); Ta = tapsA(Pa);
    Pb = pre4(s[21]);
    const float4 t20 = consA(Pa, Ta); Tb = tapsA(Pb);
    Pa = pre4(s[22]);
    const float4 t21 = consA(Pb, Tb); Ta = tapsA(Pa);
    Pb = pre4(s[23]);
    const float4 t22 = consA(Pa, Ta); Tb = tapsA(Pb);
    Pa = pre4(s[24]);
    const float4 t23 = consA(Pb, Tb); Ta = tapsA(Pa);
    const float4 t24 = consA(Pa, Ta);

    const float4 mI0 = f4mul(c0, invNv);
    const float4 mI1 = f4mul(c1, invNv);
    const float4 mI2 = f4mul(c2, invNv);
#define M(a, b) f4mul(a, b)
    const float4 rr = f4adds(f4sub(M(t19, invNv), M(mI0, mI0)), EPSF);
    const float4 rg = f4sub(M(t20, invNv), M(mI0, mI1));
    const float4 rb = f4sub(M(t21, invNv), M(mI0, mI2));
    const float4 gg = f4adds(f4sub(M(t22, invNv), M(mI1, mI1)), EPSF);
    const float4 gb = f4sub(M(t23, invNv), M(mI1, mI2));
    const float4 bb = f4adds(f4sub(M(t24, invNv), M(mI2, mI2)), EPSF);
    const float4 det = f4sub(
        f4sub(f4sub(f4add(M(M(rr, gg), bb), f4scale(M(M(rg, gb), rb), 2.f)),
                    M(M(rb, gg), rb)),
              M(M(rg, rg), bb)),
        M(M(rr, gb), gb));
    const float4 idet =
        make_float4(1.f / det.x, 1.f / det.y, 1.f / det.z, 1.f / det.w);
    const float4 iv0 = M(f4sub(M(gg, bb), M(gb, gb)), idet);
    const float4 iv1 = M(f4sub(M(rb, gb), M(rg, bb)), idet);
    const float4 iv2 = M(f4sub(M(rg, gb), M(rb, gg)), idet);
    const float4 iv3 = M(f4sub(M(rr, bb), M(rb, rb)), idet);
    const float4 iv4 = M(f4sub(M(rb, rg), M(rr, gb)), idet);
    const float4 iv5 = M(f4sub(M(rr, gg), M(rg, rg)), idet);

    // ---- per-src-channel: 4 A-chains -> solve -> 4 B-chains, pipelined;
    //      pack (a0,a1,a2,b) per col and store 4x float4 = 64B/lane ----
#pragma unroll
    for (int cc = 0; cc < 4; ++cc) {
      float4 Pc = pre4(s[3 + cc]); TapsA Tc = tapsA(Pc);
      float4 Pd = pre4(s[7 + cc]);
      const float4 tmp = consA(Pc, Tc); TapsA Td = tapsA(Pd);
      Pc = pre4(s[11 + cc]);
      const float4 tq0 = consA(Pd, Td); Tc = tapsA(Pc);
      Pd = pre4(s[15 + cc]);
      const float4 tq1 = consA(Pc, Tc); Td = tapsA(Pd);
      const float4 tq2 = consA(Pd, Td);

      const float4 m = M(tmp, invNv);
      const float4 cv0 = f4sub(M(tq0, invNv), M(mI0, m));
      const float4 cv1 = f4sub(M(tq1, invNv), M(mI1, m));
      const float4 cv2 = f4sub(M(tq2, invNv), M(mI2, m));
      float4 a0 = f4add(f4add(M(cv0, iv0), M(cv1, iv1)), M(cv2, iv2));
      float4 a1 = f4add(f4add(M(cv0, iv1), M(cv1, iv3)), M(cv2, iv4));
      float4 a2 = f4add(f4add(M(cv0, iv2), M(cv1, iv4)), M(cv2, iv5));
      float4 bv = f4sub(m, f4add(f4add(M(a0, mI0), M(a1, mI1)), M(a2, mI2)));
      a0 = abok ? a0 : Z4;
      a1 = abok ? a1 : Z4;
      a2 = abok ? a2 : Z4;
      bv = abok ? bv : Z4;

      float4 Qa = pre4(a0); TapsB Ua = tapsB(Qa);
      float4 Qb = pre4(a1);
      const float4 oa0 = consB(Qa, Ua); TapsB Ub = tapsB(Qb);
      Qa = pre4(a2);
      const float4 oa1 = consB(Qb, Ub); Ua = tapsB(Qa);
      Qb = pre4(bv);
      const float4 oa2 = consB(Qa, Ua); Ub = tapsB(Qb);
      const float4 ob = consB(Qb, Ub);

      if (stok) {
        float* po = wsb + (size_t)cc * 4 * HWSZ +
                    ((size_t)row * WW + F + 4 * lane) * 4;
        *(float4*)(po + 0)  = make_float4(oa0.x, oa1.x, oa2.x, ob.x);
        *(float4*)(po + 4)  = make_float4(oa0.y, oa1.y, oa2.y, ob.y);
        *(float4*)(po + 8)  = make_float4(oa0.z, oa1.z, oa2.z, ob.z);
        *(float4*)(po + 12) = make_float4(oa0.w, oa1.w, oa2.w, ob.w);
      }
    }
#undef M

    row_acc(row + RAD + 1, true);
    row_acc(row - RAD, false);
  }
}

// ---------------- K_B: vertical box of packed a/b + combine, channel-split.
// blockIdx.z = bi*4 + cc; one float4 load per row-step (a0,a1,a2,b).
__global__ __launch_bounds__(256) void k_vbox_comb(const float* __restrict__ ws_,
                                                   const float* __restrict__ g,
                                                   float* __restrict__ out, int b0) {
  const int col = blockIdx.x * 256 + threadIdx.x;
  const int y0 = blockIdx.y * V3R;
  const int zz = blockIdx.z;
  const int bi = zz >> 2;
  const int cc = zz & 3;
  const int b = b0 + bi;
  const float* Pp = ws_ + (size_t)bi * NPLB * HWSZ + (size_t)cc * 4 * HWSZ;
  const float* gp0 = g + (size_t)(b * 3 + 0) * HWSZ;
  const float* gp1 = g + (size_t)(b * 3 + 1) * HWSZ;
  const float* gp2 = g + (size_t)(b * 3 + 2) * HWSZ;
  float* op = out + (size_t)(b * 4 + cc) * HWSZ;

  float4 acc = make_float4(0.f, 0.f, 0.f, 0.f);
  auto row_op = [&](int y, bool add) {
    const float4 v = *(const float4*)(Pp + ((size_t)y * WW + col) * 4);
    acc = add ? f4add(acc, v) : f4sub(acc, v);
  };

  for (int yy = y0 - RAD; yy <= y0 + RAD; ++yy)
    if (yy >= 0 && yy < HH) row_op(yy, true);

  const int nx = min(col + RAD, WW - 1) - max(col - RAD, 0) + 1;
  const float invnx = 1.0f / (float)nx;

  for (int y = y0; y < y0 + V3R; ++y) {
    const int ny = min(y + RAD, HH - 1) - max(y - RAD, 0) + 1;
    const float invN = invnx / (float)ny;
    const size_t off = (size_t)y * WW + col;
    const float g0 = gp0[off], g1 = gp1[off], g2 = gp2[off];
    op[off] = (acc.x * g0 + acc.y * g1 + acc.z * g2 + acc.w) * invN;
    const int ye = y + RAD + 1;
    if (ye < HH) row_op(ye, true);
    const int yl = y - RAD;
    if (yl >= 0) row_op(yl, false);
  }
}

extern "C" void kernel_launch(void* const* d_in, const int* in_sizes, int n_in,
                              void* d_out, int out_size, void* d_ws, size_t ws_size,
                              hipStream_t stream) {
  const float* x = (const float*)d_in[0];   // (4,4,1024,1024) src p
  const float* g = (const float*)d_in[1];   // (4,3,1024,1024) guide
  float* out = (float*)d_out;
  float* ws = (float*)d_ws;
  const size_t perBatchBytes = (size_t)NPLB * HWSZ * sizeof(float);  // 64 MB
  int nb = (int)(ws_size / perBatchBytes);
  if (nb < 1) nb = 1;
  if (nb > 4) nb = 4;
  for (int b0 = 0; b0 < 4; b0 += nb) {
    const int nbc = (4 - b0 < nb) ? (4 - b0) : nb;
    dim3 gA((HH / RROWS) * NTL / 4, nbc);
    dim3 gB(WW / 256, HH / V3R, nbc * 4);
    hipLaunchKernelGGL(k_stats_solve, gA, dim3(256), 0, stream, x, g, ws, b0);
    hipLaunchKernelGGL(k_vbox_comb, gB, dim3(256), 0, stream, ws, g, out, b0);
  }
}